// Round 10
// baseline (211.454 us; speedup 1.0000x reference)
//
#include <hip/hip_runtime.h>
#include <float.h>

#define NROWS 65536
#define DK 256
#define NCODES 1024
#define FLAG_CAP 8192
#define MARGIN1 0.15f   // f16 single-pass: sigma_d ~0.0065 -> 23 sigma + granule 0.0156
#define D_BIAS 384.0f   // d = enorm + 384 - 2acc in (394, 894): 8-bit pack granule <= 2^-6

#define LOSS_OFF 16777216
#define IDX_OFF  16777217

#define CHUNK_STRIDE 1040

// ---------------- ws layout (bytes) ----------------
// High-water 1,356,304 B — identical to R3/R5/R7-R9 (proven in-bounds).
#define WS_FLAG1   0        // int
#define WS_LOSSP   8        // double[64]
#define WS_ENORMD  520      // double[1024] -> ends 8712
#define WS_ENORMF  8720     // float[1024]  -> ends 12816 (16B aligned)
#define WS_FROWS   12816    // int[FLAG_CAP] -> ends 45584
#define WS_IDX     45584    // int[65536]    -> ends 307728
#define WS_EHI     307728   // fp16[1024*256] frag-swizzled (512 KB), dead after dist_core
#define WS_ET      307728   // float[256][1024] Et (1 MB) OVERLAYS Ehi -> ends 1356304

typedef _Float16 f16x8 __attribute__((ext_vector_type(8)));
typedef float f32x4 __attribute__((ext_vector_type(4)));
typedef unsigned int uint32;

__device__ __forceinline__ uint32 packh2(float a, float b) {
  return (uint32)__builtin_bit_cast(unsigned short, (_Float16)a) |
         ((uint32)__builtin_bit_cast(unsigned short, (_Float16)b) << 16);
}

// ---- init: counters, fp64 E norms, E -> f16 fragment-swizzled Ehi ----
__global__ __launch_bounds__(256) void init_kernel(
    const float* __restrict__ E, double* __restrict__ enorm_d,
    float* __restrict__ enorm_f, uint4* __restrict__ Ehi,
    int* __restrict__ flag1, double* __restrict__ loss_part) {
  const int t = threadIdx.x;
  const int c = blockIdx.x * 8 + (t >> 5);
  const int g = t & 31;  // 8-element group within the code row
  if (blockIdx.x == 0) {
    if (t == 0) *flag1 = 0;
    if (t < 64) loss_part[t] = 0.0;
  }
  const float4* er4 = (const float4*)(E + (size_t)c * DK);
  const float4 va = er4[g * 2];
  const float4 vb = er4[g * 2 + 1];
  double s = (double)va.x * va.x + (double)va.y * va.y + (double)va.z * va.z + (double)va.w * va.w
           + (double)vb.x * vb.x + (double)vb.y * vb.y + (double)vb.z * vb.z + (double)vb.w * vb.w;
  uint4 h;
  h.x = packh2(va.x, va.y);
  h.y = packh2(va.z, va.w);
  h.z = packh2(vb.x, vb.y);
  h.w = packh2(vb.z, vb.w);
  const int ctg = c >> 8, cga = (c >> 4) & 15, col = c & 15;
  const int kc = g >> 2, quad = g & 3;
  Ehi[((size_t)((ctg * 8 + kc) * 16 + cga)) * 64 + (size_t)(quad * 16 + col)] = h;
  #pragma unroll
  for (int m = 1; m < 32; m <<= 1) s += __shfl_xor(s, m, 64);
  if (g == 0) {
    enorm_d[c] = s;
    enorm_f[c] = (float)s;
  }
}

// ---- phase 1a: f16 MFMA distances + top-2 argmin -> idx/flags ONLY ----
// R10 split: R9 PMC showed dist_fused at 1.9 TB/s (24% HBM duty) — the HBM
// bursts (stage / tail) serialize against the L2-bound MFMA middle with only
// 2-3 blocks/CU to interleave. The 67 MB out-write + loss tail moves to
// gather_out (a pure streaming kernel at 32 waves/CU); dist_core keeps only
// the 0.3 MB idx writes.
__global__ __launch_bounds__(256, 3) void dist_core(
    const float* __restrict__ X, const uint4* __restrict__ Ehi,
    const float* __restrict__ enorm_f, int* __restrict__ idx_ws,
    int* __restrict__ flag1, int* __restrict__ flag_rows,
    float* __restrict__ out) {
  __shared__ __attribute__((aligned(16))) char lds[33280];
  const int tid = threadIdx.x;
  const int lane = tid & 63;
  const int wid = tid >> 6;
  const int col = lane & 15;
  const int rowBase = blockIdx.x * 64;

  // stage A: 64 rows x 256 k, fp32 -> fp16 RNE, fragment order (rotated chunks)
  {
    const float4* X4 = (const float4*)X + (size_t)rowBase * 64;
    #pragma unroll
    for (int i = 0; i < 16; ++i) {
      const int f4 = i * 256 + tid;
      const int row = f4 >> 6;
      const int k0 = (f4 & 63) << 2;
      const float4 v = X4[f4];
      uint2 p;
      p.x = packh2(v.x, v.y);
      p.y = packh2(v.z, v.w);
      const int chunk = (row >> 4) * 8 + (k0 >> 5);
      const int off = chunk * CHUNK_STRIDE
                      + (((k0 >> 3) & 3) * 16 + (row & 15)) * 16
                      + ((k0 >> 2) & 1) * 8;
      *(uint2*)(lds + off) = p;
    }
  }
  __syncthreads();

  float rv1[16], rv2[16];  // packed top-2 per row; wave-local idx in low 8 bits
  #pragma unroll
  for (int i = 0; i < 16; ++i) { rv1[i] = FLT_MAX; rv2[i] = FLT_MAX; }

  f32x4 acc[4][4];
  #pragma unroll
  for (int rg = 0; rg < 4; ++rg)
    #pragma unroll
    for (int cg = 0; cg < 4; ++cg) acc[rg][cg] = (f32x4){0.f, 0.f, 0.f, 0.f};

  f16x8 bhA[4], bhB[4];
  auto loadB_ = [&](int t, f16x8* bh) {
    const size_t ub = ((size_t)(t * 16 + wid * 4)) * 64 + (size_t)lane;
    #pragma unroll
    for (int cg = 0; cg < 4; ++cg) bh[cg] = *(const f16x8*)&Ehi[ub + (size_t)cg * 64];
  };
  auto loadA_ = [&](int t, f16x8* av) {
    const int ks = t & 7;
    #pragma unroll
    for (int rg = 0; rg < 4; ++rg)
      av[rg] = *(const f16x8*)(lds + (rg * 8 + ks) * CHUNK_STRIDE + lane * 16);
  };
  auto domfma = [&](f16x8* av, f16x8* bh) {
    #pragma unroll
    for (int rg = 0; rg < 4; ++rg)
      #pragma unroll
      for (int cg = 0; cg < 4; ++cg)
        acc[rg][cg] = __builtin_amdgcn_mfma_f32_16x16x32_f16(av[rg], bh[cg], acc[rg][cg], 0, 0, 0);
  };
  auto epilogue = [&](int ctg) {
    #pragma unroll
    for (int cg = 0; cg < 4; ++cg) {
      const int code = ctg * 256 + wid * 64 + cg * 16 + col;
      const float en = enorm_f[code] + D_BIAS;
      const uint32 li = (uint32)((ctg << 6) | (cg << 4) | col);
      #pragma unroll
      for (int rg = 0; rg < 4; ++rg)
        #pragma unroll
        for (int reg = 0; reg < 4; ++reg) {
          const int i = rg * 4 + reg;
          const float dd = fmaf(-2.0f, acc[rg][cg][reg], en);
          const float p = __builtin_bit_cast(float,
              (__builtin_bit_cast(uint32, dd) & 0xFFFFFF00u) | li);
          rv2[i] = __builtin_amdgcn_fmed3f(p, rv1[i], rv2[i]);
          rv1[i] = fminf(rv1[i], p);
        }
    }
    #pragma unroll
    for (int rg = 0; rg < 4; ++rg)
      #pragma unroll
      for (int cg = 0; cg < 4; ++cg) acc[rg][cg] = (f32x4){0.f, 0.f, 0.f, 0.f};
  };

  loadB_(0, bhA);
  f16x8 av[4];
  for (int tt = 0; tt < 32; tt += 2) {
    loadB_(tt + 1, bhB);
    loadA_(tt, av);
    domfma(av, bhA);
    if (tt + 2 < 32) loadB_(tt + 2, bhA);
    loadA_(tt + 1, av);
    domfma(av, bhB);
    if (((tt + 1) & 7) == 7) epilogue(tt >> 3);
  }

  // merge 16 cols within each quad (packed => lowest local idx wins ties)
  #pragma unroll
  for (int i = 0; i < 16; ++i) {
    #pragma unroll
    for (int m = 1; m < 16; m <<= 1) {
      const float o1 = __shfl_xor(rv1[i], m, 64);
      const float o2 = __shfl_xor(rv2[i], m, 64);
      rv2[i] = fminf(fminf(rv2[i], o2), fmaxf(rv1[i], o1));
      rv1[i] = fminf(rv1[i], o1);
    }
  }

  __syncthreads();  // all waves done reading A region
  float* M = (float*)lds;  // [row 64][wave 4][2]  (2 KB)
  if (col == 0) {
    const int quad = lane >> 4;
    #pragma unroll
    for (int i = 0; i < 16; ++i) {
      const int row = (i >> 2) * 16 + quad * 4 + (i & 3);
      M[(row * 4 + wid) * 2 + 0] = rv1[i];
      M[(row * 4 + wid) * 2 + 1] = rv2[i];
    }
  }
  __syncthreads();
  if (tid < 64) {
    const float a1 = M[(tid * 4 + 0) * 2], a2 = M[(tid * 4 + 0) * 2 + 1];
    const float b1 = M[(tid * 4 + 1) * 2], b2 = M[(tid * 4 + 1) * 2 + 1];
    const float c1 = M[(tid * 4 + 2) * 2], c2 = M[(tid * 4 + 2) * 2 + 1];
    const float d1 = M[(tid * 4 + 3) * 2], d2 = M[(tid * 4 + 3) * 2 + 1];
    const float lo1 = fminf(a1, b1), hi1 = fmaxf(a1, b1);
    const float lo2 = fminf(c1, d1), hi2 = fmaxf(c1, d1);
    const float r1 = fminf(lo1, lo2);
    const float s1 = fminf(fmaxf(lo1, lo2), fminf(hi1, hi2));
    const float r2 = fminf(fminf(fminf(a2, b2), fminf(c2, d2)), s1);
    const int w1 = (r1 == a1) ? 0 : (r1 == b1) ? 1 : (r1 == c1) ? 2 : 3;
    const uint32 u1 = __builtin_bit_cast(uint32, r1);
    const int li = (int)(u1 & 255u);
    const int code = ((li >> 6) & 3) * 256 + w1 * 64 + ((li >> 4) & 3) * 16 + (li & 15);
    const int row = rowBase + tid;
    idx_ws[row] = code;
    out[IDX_OFF + row] = (float)code;
    const float q1 = __builtin_bit_cast(float, u1 & 0xFFFFFF00u);
    const float q2 = __builtin_bit_cast(float, __builtin_bit_cast(uint32, r2) & 0xFFFFFF00u);
    if (q2 - q1 < MARGIN1) {
      const int p = atomicAdd(flag1, 1);
      if (p < FLAG_CAP) flag_rows[p] = row;
    }
  }
}

// ---- phase 1b: streaming gather/write/loss (provisional idx) ----
// Pure HBM streamer: 2048 blocks x 4 waves = 32 waves/CU. Per row: idx
// broadcast, E-row gather (L2: E is 1 MB), X re-read (L3: just streamed by
// dist_core), coalesced 67 MB out write, exact fp64 loss partials.
// fixup_split later rewrites flagged rows and adjusts loss by the delta.
__global__ __launch_bounds__(256) void gather_out(
    const float* __restrict__ X, const float* __restrict__ E,
    const int* __restrict__ idx_ws, float* __restrict__ out,
    double* __restrict__ loss_part) {
  const int lane = threadIdx.x & 63;
  const int wid = threadIdx.x >> 6;
  const int gw = blockIdx.x * 4 + wid;
  const int nw = gridDim.x * 4;
  double ls = 0.0;
  #pragma unroll 2
  for (int row = gw; row < NROWS; row += nw) {
    const int idx = idx_ws[row];
    const float4 q = ((const float4*)E)[(size_t)idx * 64 + lane];
    const float4 x = ((const float4*)X)[(size_t)row * 64 + lane];
    ((float4*)out)[(size_t)row * 64 + lane] = q;
    const double d0 = (double)q.x - (double)x.x;
    const double d1 = (double)q.y - (double)x.y;
    const double d2 = (double)q.z - (double)x.z;
    const double d3 = (double)q.w - (double)x.w;
    ls += d0 * d0 + d1 * d1 + d2 * d2 + d3 * d3;
  }
  #pragma unroll
  for (int o = 32; o > 0; o >>= 1) ls += __shfl_down(ls, o, 64);
  __shared__ double wsum[4];
  if (lane == 0) wsum[wid] = ls;
  __syncthreads();
  if (threadIdx.x == 0)
    atomicAdd(&loss_part[blockIdx.x & 63], wsum[0] + wsum[1] + wsum[2] + wsum[3]);
}

// ---- E transpose: LDS-tiled 64x64, 64 blocks ----
__global__ __launch_bounds__(256) void transposeE(
    const float* __restrict__ E, float* __restrict__ Et) {
  __shared__ float tile[64][65];
  const int t = threadIdx.x;
  const int c0 = (blockIdx.x & 15) * 64;
  const int k0 = (blockIdx.x >> 4) * 64;
  {
    const int c = t & 63, q = t >> 6;
    const float4* src = (const float4*)(E + (size_t)(c0 + c) * DK + k0 + q * 16);
    #pragma unroll
    for (int j = 0; j < 4; ++j) {
      const float4 v = src[j];
      const int kk = q * 16 + j * 4;
      tile[kk + 0][c] = v.x;
      tile[kk + 1][c] = v.y;
      tile[kk + 2][c] = v.z;
      tile[kk + 3][c] = v.w;
    }
  }
  __syncthreads();
  {
    const int kk = t >> 2, cq = (t & 3) * 16;
    float4* dst = (float4*)(Et + (size_t)(k0 + kk) * NCODES + c0 + cq);
    #pragma unroll
    for (int j = 0; j < 4; ++j) {
      dst[j] = (float4){tile[kk][cq + j * 4 + 0], tile[kk][cq + j * 4 + 1],
                        tile[kk][cq + j * 4 + 2], tile[kk][cq + j * 4 + 3]};
    }
  }
}

// ---- phase 2: fp64 split-k re-resolution, 2 rows per 256-thr block ----
// (R9-proven: wave w owns k in [64w,64w+64); fp64 from the start = the old
// tie path for ALL flagged rows; no serial-256 chain anywhere.)
__global__ __launch_bounds__(256, 2) void fixup_split(
    const float* __restrict__ X, const float* __restrict__ E,
    const float* __restrict__ Et, const double* __restrict__ enorm_d,
    const int* __restrict__ flag1, const int* __restrict__ flag_rows,
    const int* __restrict__ idx_ws, float* __restrict__ out,
    double* __restrict__ loss_part) {
  __shared__ double pacc[NCODES * 3];  // [code]{r0,r1,pad} 24 KB
  __shared__ double xd[256][2];        // 4 KB
  __shared__ double red[256];          // 2 KB
  __shared__ double wv[4][2];
  __shared__ int wi[4][2];
  __shared__ int rowL[2], oldL[2], newsh[2];
  const int tid = threadIdx.x;
  const int lane = tid & 63, wid = tid >> 6;
  int cnt = *flag1;
  if (cnt > FLAG_CAP) cnt = FLAG_CAP;
  const int ngroups = (cnt + 1) >> 1;

  for (int g = blockIdx.x; g < ngroups; g += gridDim.x) {
    const int fbase = g * 2;
    const int nr = min(2, cnt - fbase);
    __syncthreads();  // protect shared reuse across grid-stride iterations
    if (tid < 2) {
      const int fi = fbase + tid;
      const int row = (tid < nr) ? flag_rows[fi] : flag_rows[fbase];
      rowL[tid] = row;
      oldL[tid] = idx_ws[row];
    }
    __syncthreads();
    xd[tid][0] = (double)X[(size_t)rowL[0] * DK + tid];
    xd[tid][1] = (double)X[(size_t)rowL[1] * DK + tid];
    __syncthreads();

    double acc[4][4][2];  // [q][j][r]
    #pragma unroll
    for (int q = 0; q < 4; ++q)
      #pragma unroll
      for (int j = 0; j < 4; ++j) { acc[q][j][0] = 0.0; acc[q][j][1] = 0.0; }
    const f32x4* Et4 = (const f32x4*)Et;
    #pragma unroll 2
    for (int kk = 0; kk < 64; ++kk) {
      const int k = (wid << 6) + kk;
      f32x4 e[4];
      #pragma unroll
      for (int q = 0; q < 4; ++q)
        e[q] = Et4[(size_t)k * 256 + (lane << 2) + q];
      const double x0 = xd[k][0], x1 = xd[k][1];
      #pragma unroll
      for (int q = 0; q < 4; ++q)
        #pragma unroll
        for (int j = 0; j < 4; ++j) {
          const double ed = (double)e[q][j];
          acc[q][j][0] = fma(ed, x0, acc[q][j][0]);
          acc[q][j][1] = fma(ed, x1, acc[q][j][1]);
        }
    }
    for (int w = 0; w < 4; ++w) {
      if (wid == w) {
        #pragma unroll
        for (int q = 0; q < 4; ++q)
          #pragma unroll
          for (int j = 0; j < 4; ++j) {
            const int c = (lane << 4) + (q << 2) + j;
            if (w == 0) {
              pacc[c * 3 + 0] = acc[q][j][0];
              pacc[c * 3 + 1] = acc[q][j][1];
            } else {
              pacc[c * 3 + 0] += acc[q][j][0];
              pacc[c * 3 + 1] += acc[q][j][1];
            }
          }
      }
      __syncthreads();
    }

    double bd[2] = {1e300, 1e300};
    int bi[2] = {0x7fffffff, 0x7fffffff};
    #pragma unroll
    for (int m = 0; m < 4; ++m) {
      const int c = tid + (m << 8);
      const double en = enorm_d[c];
      #pragma unroll
      for (int r = 0; r < 2; ++r) {
        const double d = en - 2.0 * pacc[c * 3 + r];
        if (d < bd[r] || (d == bd[r] && c < bi[r])) { bd[r] = d; bi[r] = c; }
      }
    }
    #pragma unroll
    for (int r = 0; r < 2; ++r) {
      double v = bd[r];
      int i = bi[r];
      #pragma unroll
      for (int m = 1; m < 64; m <<= 1) {
        const double ov = __shfl_xor(v, m, 64);
        const int oi = __shfl_xor(i, m, 64);
        if (ov < v || (ov == v && oi < i)) { v = ov; i = oi; }
      }
      if (lane == 0) { wv[wid][r] = v; wi[wid][r] = i; }
    }
    __syncthreads();
    if (tid < 2) {
      double B = wv[0][tid];
      int I = wi[0][tid];
      #pragma unroll
      for (int w = 1; w < 4; ++w) {
        if (wv[w][tid] < B || (wv[w][tid] == B && wi[w][tid] < I)) {
          B = wv[w][tid];
          I = wi[w][tid];
        }
      }
      newsh[tid] = I;
    }
    __syncthreads();

    for (int r = 0; r < nr; ++r) {
      const int newi = newsh[r];
      const int oldi = oldL[r];
      if (newi != oldi) {  // block-uniform
        const int row = rowL[r];
        const double x = xd[tid][r];
        const float ev = E[(size_t)newi * DK + tid];
        const float eo = E[(size_t)oldi * DK + tid];
        out[(size_t)row * DK + tid] = ev;
        const double dn = (double)ev - x;
        const double dl = (double)eo - x;
        red[tid] = dn * dn - dl * dl;
        __syncthreads();
        for (int off = 128; off > 0; off >>= 1) {
          if (tid < off) red[tid] += red[tid + off];
          __syncthreads();
        }
        if (tid == 0) {
          out[IDX_OFF + row] = (float)newi;
          atomicAdd(&loss_part[row & 63], red[0]);
        }
        __syncthreads();
      }
    }
  }
}

__global__ __launch_bounds__(64) void finalize(
    const double* __restrict__ loss_part, float* __restrict__ out) {
  double v = loss_part[threadIdx.x];
  for (int o = 32; o > 0; o >>= 1) v += __shfl_down(v, o, 64);
  if (threadIdx.x == 0) out[LOSS_OFF] = (float)(v / 16777216.0);
}

extern "C" void kernel_launch(void* const* d_in, const int* in_sizes, int n_in,
                              void* d_out, int out_size, void* d_ws, size_t ws_size,
                              hipStream_t stream) {
  const float* X = (const float*)d_in[0];  // [65536, 256]
  const float* E = (const float*)d_in[1];  // [1024, 256]
  float* out = (float*)d_out;
  char* ws = (char*)d_ws;

  int*    flag1     = (int*)(ws + WS_FLAG1);
  double* loss_part = (double*)(ws + WS_LOSSP);
  double* enorm_d   = (double*)(ws + WS_ENORMD);
  float*  enorm_f   = (float*)(ws + WS_ENORMF);
  int*    flag_rows = (int*)(ws + WS_FROWS);
  int*    idx_ws    = (int*)(ws + WS_IDX);
  uint4*  Ehi       = (uint4*)(ws + WS_EHI);
  float*  Et        = (float*)(ws + WS_ET);

  hipLaunchKernelGGL(init_kernel, dim3(128), dim3(256), 0, stream,
                     E, enorm_d, enorm_f, Ehi, flag1, loss_part);
  hipLaunchKernelGGL(dist_core, dim3(NROWS / 64), dim3(256), 0, stream,
                     X, Ehi, enorm_f, idx_ws, flag1, flag_rows, out);
  hipLaunchKernelGGL(gather_out, dim3(2048), dim3(256), 0, stream,
                     X, E, idx_ws, out, loss_part);
  // Et overlays Ehi (dead after dist_core)
  hipLaunchKernelGGL(transposeE, dim3(64), dim3(256), 0, stream, E, Et);
  hipLaunchKernelGGL(fixup_split, dim3(FLAG_CAP / 2), dim3(256), 0, stream,
                     X, E, Et, enorm_d, flag1, flag_rows, idx_ws, out, loss_part);
  hipLaunchKernelGGL(finalize, dim3(1), dim3(64), 0, stream, loss_part, out);
}